// Round 4
// baseline (411.412 us; speedup 1.0000x reference)
//
#include <hip/hip_runtime.h>

// MoE forward, MI355X. fp32 router/dispatch (exact top-k), bf16 MFMA grouped
// GEMMs (9 groups = 8 experts + shared), fp32-atomic scatter-combine.
// R3: bigger rectangular tiles (GEMM1 256x128, GEMM2 128x256, 8 waves, 96KB
// dbuf LDS) to cut cache-side staging bytes/flop; stage pinned before compute
// via sched_barrier(0); setprio around MFMA cluster. Swizzle + XCD remap kept.

#define NTOK 8192
#define DDIM 1024
#define HDIM 1408
#define CAP  2560
#define NROWS (NTOK + 8*CAP)   // 28672 GEMM rows: [0,8192) shared, then 8*2560 expert slots
#define YN   8388608           // NTOK*DDIM

typedef __bf16 bf16x8 __attribute__((ext_vector_type(8)));
typedef float  f32x4  __attribute__((ext_vector_type(4)));

typedef __attribute__((address_space(1))) void gvoid_t;
typedef __attribute__((address_space(3))) void svoid_t;

static __device__ __forceinline__ void load_lds16(const void* g, void* l) {
  // 16B per lane, LDS dest = wave-uniform base + lane*16 (linear)
  __builtin_amdgcn_global_load_lds((gvoid_t*)g, (svoid_t*)l, 16, 0, 0);
}

// ---------------- zero y + aux + accumulators ----------------
__global__ __launch_bounds__(256) void zero_kernel(float* __restrict__ y,
                                                   float* __restrict__ psum,
                                                   int* __restrict__ fcnt) {
  size_t idx = (size_t)blockIdx.x * 256 + threadIdx.x;
  float4 z = make_float4(0.f, 0.f, 0.f, 0.f);
  float4* p = (float4*)y;
#pragma unroll
  for (int j = 0; j < 4; ++j) p[idx + (size_t)j * 524288] = z;
  if (idx == 0) {
    y[YN] = 0.f;
    for (int e = 0; e < 8; ++e) { psum[e] = 0.f; fcnt[e] = 0; }
  }
}

// ---------------- fp32 -> bf16 (x) ----------------
__global__ __launch_bounds__(256) void convx_kernel(const float* __restrict__ in,
                                                    __bf16* __restrict__ out) {
  size_t i = ((size_t)blockIdx.x * 256 + threadIdx.x) * 8;
  float4 a = *(const float4*)(in + i);
  float4 b = *(const float4*)(in + i + 4);
  bf16x8 o;
  o[0] = (__bf16)a.x; o[1] = (__bf16)a.y; o[2] = (__bf16)a.z; o[3] = (__bf16)a.w;
  o[4] = (__bf16)b.x; o[5] = (__bf16)b.y; o[6] = (__bf16)b.z; o[7] = (__bf16)b.w;
  *(bf16x8*)(out + i) = o;
}

// ---------------- transpose + convert weights: in[R][C] f32 -> out[C][R] bf16 ----------------
__global__ __launch_bounds__(256) void tconv_kernel(const float* __restrict__ in,
                                                    __bf16* __restrict__ out, int R, int C) {
  __shared__ float t[32][33];
  size_t mo = (size_t)blockIdx.z * R * C;
  const float* ip = in + mo;
  __bf16* op = out + mo;
  int c0 = blockIdx.x * 32, r0 = blockIdx.y * 32;
  int tx = threadIdx.x, ty = threadIdx.y;  // block (32,8)
#pragma unroll
  for (int k2 = 0; k2 < 4; ++k2)
    t[ty + k2 * 8][tx] = ip[(size_t)(r0 + ty + k2 * 8) * C + c0 + tx];
  __syncthreads();
#pragma unroll
  for (int k2 = 0; k2 < 4; ++k2)
    op[(size_t)(c0 + ty + k2 * 8) * R + r0 + tx] = (__bf16)t[tx][ty + k2 * 8];
}

// ---------------- router: fp32 logits, softmax, top-2, renorm, aux stats ----------------
__global__ __launch_bounds__(256) void router_kernel(
    const float* __restrict__ x, const float* __restrict__ rw,
    int2* __restrict__ e01, float2* __restrict__ p01,
    int* __restrict__ tok_row, float* __restrict__ scale_row,
    float* __restrict__ psum, int* __restrict__ fcnt) {
  __shared__ float rwl[8 * 1024];
  __shared__ float ps[8];
  __shared__ int fc[8];
  int tid = threadIdx.x;
  if (tid < 8) { ps[tid] = 0.f; fc[tid] = 0; }
  float4* rl4 = (float4*)rwl;
  const float4* rg4 = (const float4*)rw;
#pragma unroll
  for (int j = 0; j < 8; ++j) rl4[tid + 256 * j] = rg4[tid + 256 * j];
  __syncthreads();
  int lane = tid & 63, wid = tid >> 6;
  for (int it = 0; it < 8; ++it) {
    int t = blockIdx.x * 32 + wid * 8 + it;
    const float4* xt = (const float4*)(x + (size_t)t * DDIM);
    float a[8];
#pragma unroll
    for (int e = 0; e < 8; ++e) a[e] = 0.f;
#pragma unroll
    for (int jj = 0; jj < 4; ++jj) {
      float4 v = xt[lane * 4 + jj];
#pragma unroll
      for (int e = 0; e < 8; ++e) {
        float4 w = rl4[e * 256 + lane * 4 + jj];
        a[e] += v.x * w.x + v.y * w.y + v.z * w.z + v.w * w.w;
      }
    }
#pragma unroll
    for (int off = 32; off >= 1; off >>= 1)
#pragma unroll
      for (int e = 0; e < 8; ++e) a[e] += __shfl_xor(a[e], off);
    if (lane == 0) {
      int am = 0; float m = a[0];
      for (int e = 1; e < 8; ++e) if (a[e] > m) { m = a[e]; am = e; }
      float s = 0.f, ex[8];
      for (int e = 0; e < 8; ++e) { ex[e] = expf(a[e] - m); s += ex[e]; }
      float inv = 1.f / s;
      int am2 = -1; float m2 = -3.4e38f;
      for (int e = 0; e < 8; ++e) if (e != am && a[e] > m2) { m2 = a[e]; am2 = e; }
      float p0 = ex[am] * inv, p1 = ex[am2] * inv;
      float rn = 1.f / (p0 + p1 + 1e-9f);
      e01[t] = make_int2(am, am2);
      p01[t] = make_float2(p0 * rn, p1 * rn);
      tok_row[t] = t;            // shared-group rows: identity gather, weight 1
      scale_row[t] = 1.f;
      atomicAdd(&fc[am], 1);
      for (int e = 0; e < 8; ++e) atomicAdd(&ps[e], ex[e] * inv);
    }
  }
  __syncthreads();
  if (tid < 8) { atomicAdd(&psum[tid], ps[tid]); atomicAdd(&fcnt[tid], fc[tid]); }
}

// ---------------- dispatch: stable rank within expert (token-major order), capacity drop ----------------
__global__ __launch_bounds__(256) void dispatch_kernel(
    const int2* __restrict__ e01, const float2* __restrict__ p01,
    int* __restrict__ tok_row, float* __restrict__ scale_row, int* __restrict__ counts) {
  __shared__ int lcnt[256][8];
  int tid = threadIdx.x;
  int my[8];
#pragma unroll
  for (int e = 0; e < 8; ++e) my[e] = 0;
  int base = tid * 64;  // 256 threads * 64 entries = 16384 = N*K, contiguous => stable
  for (int j = 0; j < 64; ++j) {
    int ent = base + j; int t = ent >> 1;
    int2 ee = e01[t];
    int ex = (ent & 1) ? ee.y : ee.x;
    my[ex]++;
  }
#pragma unroll
  for (int e = 0; e < 8; ++e) lcnt[tid][e] = my[e];
  __syncthreads();
  if (tid < 8) {
    int run = 0;
    for (int i = 0; i < 256; ++i) { int c = lcnt[i][tid]; lcnt[i][tid] = run; run += c; }
    counts[tid] = run < CAP ? run : CAP;
  }
  __syncthreads();
  int offs[8];
#pragma unroll
  for (int e = 0; e < 8; ++e) offs[e] = lcnt[tid][e];
  for (int j = 0; j < 64; ++j) {
    int ent = base + j; int t = ent >> 1; int k = ent & 1;
    int2 ee = e01[t];
    int ex = k ? ee.y : ee.x;
    float pr = k ? p01[t].y : p01[t].x;
    int pos = offs[ex]++;
    if (pos < CAP) {
      int row = NTOK + ex * CAP + pos;
      tok_row[row] = t;
      scale_row[row] = pr;
    }
  }
}

// ---------------- grouped GEMM, BMxBN tile, BK=64, 8 waves (512 thr), dbuf 2-phase ----------------
// WNV = waves along N (WM = 8/WNV along M); per-wave tile 64x64 (4x4 frags).
// Groups: g=0..7 experts (rows via tok_row), g=8 shared. B bf16 [9][NDT][KD].
// XOR chunk-swizzle on stage source + LDS reads (R2-verified, 0 conflicts).
// EPI==1: H = bf16(relu(acc)^2)   EPI==2: atomicAdd(y[tok][col], acc*scale)
template <int BM, int BN, int KD, int NDT, int WNV, bool GATHER, int EPI>
__global__ __launch_bounds__(512, 2) void gemm_kernel(
    const __bf16* __restrict__ A, const __bf16* __restrict__ B,
    __bf16* __restrict__ Hout, float* __restrict__ Yout,
    const int* __restrict__ counts, const int* __restrict__ tok_row,
    const float* __restrict__ scale_row) {
  constexpr int NCT = NDT / BN;
  constexpr int NT = KD / 64;
  constexpr int SH = NTOK / BM;   // shared row-tiles
  constexpr int ET = CAP / BM;    // worst-case expert row-tiles
  // XCD bijective remap + 4-rt chunks (nwg%8==0 and nwg%(4*NCT)==0 hold)
  int nwg = gridDim.x;
  int lin = (blockIdx.x & 7) * (nwg >> 3) + (blockIdx.x >> 3);
  int rem = lin % (4 * NCT);
  int rt = (lin / (4 * NCT)) * 4 + (rem & 3);
  int ct = rem >> 2;

  int g, i0, rowbase;
  if (rt < SH) { g = 8; rowbase = 0; i0 = rt * BM; }
  else { int r = rt - SH; g = r / ET; i0 = (r % ET) * BM; rowbase = NTOK + g * CAP; }
  int cnt = (g == 8) ? NTOK : counts[g];
  if (i0 >= cnt) return;  // uniform early-exit

  __shared__ __align__(16) __bf16 As[2][BM * 64];
  __shared__ __align__(16) __bf16 Bs[2][BN * 64];
  __shared__ int   toksL[BM];
  __shared__ float sclL[BM];

  int tid = threadIdx.x, lane = tid & 63, wid = tid >> 6;

  if (tid < BM) {
    int i = i0 + tid; if (i > cnt - 1) i = cnt - 1;  // pad rows duplicate last valid
    toksL[tid] = tok_row[rowbase + i];
    if (EPI == 2) sclL[tid] = scale_row[rowbase + i];
  }
  __syncthreads();

  // staging pointers: 8 lanes cover one 128B k-row; 16B chunk swizzled by row&7
  int rsub = lane >> 3, csub = lane & 7;
  int csw = (csub ^ rsub) * 16;
  const char* aP[BM / 64];
  const char* bP[BN / 64];
  const char* Bg = (const char*)B + (size_t)g * NDT * KD * 2;
#pragma unroll
  for (int t = 0; t < BM / 64; ++t) {
    int ia = wid * (BM / 8) + t * 8 + rsub;
    size_t arow = GATHER ? (size_t)toksL[ia] : (size_t)(rowbase + i0 + ia);
    aP[t] = (const char*)A + arow * (size_t)(KD * 2) + csw;
  }
#pragma unroll
  for (int t = 0; t < BN / 64; ++t) {
    int ib = ct * BN + wid * (BN / 8) + t * 8 + rsub;
    bP[t] = Bg + (size_t)ib * (KD * 2) + csw;
  }

  f32x4 acc[4][4];
#pragma unroll
  for (int m2 = 0; m2 < 4; ++m2)
#pragma unroll
    for (int n2 = 0; n2 < 4; ++n2) acc[m2][n2] = f32x4{0.f, 0.f, 0.f, 0.f};

  int wr = wid / WNV, wc = wid % WNV;   // wave tile 64x64 at (wr*64, wc*64)
  // hoisted LDS read offsets; chunk' = chunk ^ (row&7), row&7 == lane&7
  int rA[4], rB[4], cS[2];
#pragma unroll
  for (int m2 = 0; m2 < 4; ++m2) rA[m2] = (wr * 64 + m2 * 16 + (lane & 15)) * 64;
#pragma unroll
  for (int n2 = 0; n2 < 4; ++n2) rB[n2] = (wc * 64 + n2 * 16 + (lane & 15)) * 64;
#pragma unroll
  for (int kk = 0; kk < 2; ++kk) cS[kk] = ((kk * 4 + (lane >> 4)) ^ (lane & 7)) * 8;

  auto stage = [&](int buf, int k0) {
    size_t kb = (size_t)k0 * 2;
#pragma unroll
    for (int t = 0; t < BM / 64; ++t)
      load_lds16(aP[t] + kb, &As[buf][(wid * (BM / 8) + t * 8) * 64]);
#pragma unroll
    for (int t = 0; t < BN / 64; ++t)
      load_lds16(bP[t] + kb, &Bs[buf][(wid * (BN / 8) + t * 8) * 64]);
  };
  auto compute = [&](int buf) {
#pragma unroll
    for (int kk = 0; kk < 2; ++kk) {
      bf16x8 af[4], bfr[4];
#pragma unroll
      for (int m2 = 0; m2 < 4; ++m2) af[m2] = *(const bf16x8*)&As[buf][rA[m2] + cS[kk]];
#pragma unroll
      for (int n2 = 0; n2 < 4; ++n2) bfr[n2] = *(const bf16x8*)&Bs[buf][rB[n2] + cS[kk]];
#pragma unroll
      for (int m2 = 0; m2 < 4; ++m2)
#pragma unroll
        for (int n2 = 0; n2 < 4; ++n2)
          acc[m2][n2] = __builtin_amdgcn_mfma_f32_16x16x32_bf16(af[m2], bfr[n2], acc[m2][n2], 0, 0, 0);
    }
  };

  // 2-phase: stage(t+1) issued first (pinned), compute(t), one barrier/step
  stage(0, 0);
  __syncthreads();
  int cur = 0;
#pragma unroll 2
  for (int t = 0; t < NT - 1; ++t) {
    stage(cur ^ 1, (t + 1) * 64);
    __builtin_amdgcn_sched_barrier(0);   // pin stage-issue before compute
    __builtin_amdgcn_s_setprio(1);
    compute(cur);
    __builtin_amdgcn_s_setprio(0);
    __syncthreads();
    cur ^= 1;
  }
  compute(cur);

  // epilogue; C/D frag: col = lane&15, row = (lane>>4)*4 + reg  [verified m89/m91]
#pragma unroll
  for (int m2 = 0; m2 < 4; ++m2) {
    int rb = wr * 64 + m2 * 16 + ((lane >> 4) << 2);
#pragma unroll
    for (int n2 = 0; n2 < 4; ++n2) {
      int col = ct * BN + wc * 64 + n2 * 16 + (lane & 15);
#pragma unroll
      for (int r = 0; r < 4; ++r) {
        int grow = i0 + rb + r;
        if (grow < cnt) {
          float v = acc[m2][n2][r];
          if constexpr (EPI == 1) {
            v = fmaxf(v, 0.f);
            Hout[(size_t)(rowbase + grow) * NDT + col] = (__bf16)(v * v);
          } else {
            atomicAdd(&Yout[(size_t)toksL[rb + r] * NDT + col], v * sclL[rb + r]);
          }
        }
      }
    }
  }
}

// ---------------- aux loss ----------------
__global__ void aux_kernel(const float* __restrict__ psum, const int* __restrict__ fcnt,
                           float* __restrict__ out) {
  float s = 0.f;
  for (int e = 0; e < 8; ++e) s += ((float)fcnt[e] / 8192.f) * (psum[e] / 8192.f);
  *out = 0.08f * s;  // AUX_COEF * E = 0.01 * 8
}

extern "C" void kernel_launch(void* const* d_in, const int* in_sizes, int n_in,
                              void* d_out, int out_size, void* d_ws, size_t ws_size,
                              hipStream_t stream) {
  const float* x      = (const float*)d_in[0];
  const float* rw     = (const float*)d_in[1];
  const float* wfc    = (const float*)d_in[2];
  const float* wproj  = (const float*)d_in[3];
  const float* wsfc   = (const float*)d_in[4];
  const float* wsproj = (const float*)d_in[5];
  float* y = (float*)d_out;

  char* ws = (char*)d_ws;
  size_t off = 0;
  auto alloc = [&](size_t bytes) {
    void* p = ws + off;
    off += (bytes + 1023) & ~(size_t)1023;
    return p;
  };
  __bf16* xbf      = (__bf16*)alloc((size_t)NTOK * DDIM * 2);          // 16 MB
  __bf16* B1       = (__bf16*)alloc((size_t)9 * HDIM * DDIM * 2);      // 26 MB [9][1408][1024]
  __bf16* B2       = (__bf16*)alloc((size_t)9 * DDIM * HDIM * 2);      // 26 MB [9][1024][1408]
  __bf16* H        = (__bf16*)alloc((size_t)NROWS * HDIM * 2);         // 81 MB
  int*    tok_row  = (int*)alloc((size_t)NROWS * 4);
  float*  scale_row= (float*)alloc((size_t)NROWS * 4);
  int2*   e01      = (int2*)alloc((size_t)NTOK * 8);
  float2* p01      = (float2*)alloc((size_t)NTOK * 8);
  int*    counts   = (int*)alloc(1024);
  float*  psum     = (float*)alloc(1024);
  int*    fcnt     = (int*)alloc(1024);
  (void)ws_size; (void)out_size; (void)in_sizes; (void)n_in;

  zero_kernel<<<2048, 256, 0, stream>>>(y, psum, fcnt);
  convx_kernel<<<4096, 256, 0, stream>>>(x, xbf);
  dim3 tb(32, 8);
  tconv_kernel<<<dim3(44, 32, 8), tb, 0, stream>>>(wfc, B1, 1024, 1408);
  tconv_kernel<<<dim3(44, 32, 1), tb, 0, stream>>>(wsfc, B1 + (size_t)8 * HDIM * DDIM, 1024, 1408);
  tconv_kernel<<<dim3(32, 44, 8), tb, 0, stream>>>(wproj, B2, 1408, 1024);
  tconv_kernel<<<dim3(32, 44, 1), tb, 0, stream>>>(wsproj, B2 + (size_t)8 * DDIM * HDIM, 1408, 1024);
  router_kernel<<<256, 256, 0, stream>>>(x, rw, e01, p01, tok_row, scale_row, psum, fcnt);
  dispatch_kernel<<<1, 256, 0, stream>>>(e01, p01, tok_row, scale_row, counts);
  // GEMM1: H = relu(gather(x) @ B1)^2 ; 256x128 tiles: (32 + 8*10) rt * 11 ct = 1232
  gemm_kernel<256, 128, 1024, 1408, 2, true, 1><<<1232, 512, 0, stream>>>(
      xbf, B1, H, nullptr, counts, tok_row, scale_row);
  // GEMM2: y[tok] += scale * (H @ B2) ; 128x256 tiles: (64 + 8*20) rt * 4 ct = 896
  gemm_kernel<128, 256, 1408, 1024, 4, false, 2><<<896, 512, 0, stream>>>(
      H, B2, nullptr, y, counts, tok_row, scale_row);
  aux_kernel<<<1, 1, 0, stream>>>(psum, fcnt, y + YN);
}

// Round 6
// 363.355 us; speedup vs baseline: 1.1323x; 1.1323x over previous
//
#include <hip/hip_runtime.h>

// MoE forward, MI355X. fp32 router/dispatch (exact top-k), bf16 MFMA grouped
// GEMMs (9 groups = 8 experts + shared), fp32-atomic scatter-combine.
// R5: fix R4's pipeline-tail race. Depth-3 counted-vmcnt pipeline (BK=32,
// 4 LDS buffers, vmcnt(6) steady state) now drains 6->3->0 in the last three
// K-steps (R4 kept vmcnt(6) after stage issue stopped => stale LDS reads).
// sched_barrier(0) after each raw s_barrier (raw barrier isn't an LLVM fence).

#define NTOK 8192
#define DDIM 1024
#define HDIM 1408
#define CAP  2560
#define NROWS (NTOK + 8*CAP)   // 28672 GEMM rows: [0,8192) shared, then 8*2560 expert slots
#define YN   8388608           // NTOK*DDIM

typedef __bf16 bf16x8 __attribute__((ext_vector_type(8)));
typedef float  f32x4  __attribute__((ext_vector_type(4)));

typedef __attribute__((address_space(1))) void gvoid_t;
typedef __attribute__((address_space(3))) void svoid_t;

static __device__ __forceinline__ void load_lds16(const void* g, void* l) {
  // 16B per lane, LDS dest = wave-uniform base + lane*16 (linear)
  __builtin_amdgcn_global_load_lds((gvoid_t*)g, (svoid_t*)l, 16, 0, 0);
}

// ---------------- zero y + aux + accumulators ----------------
__global__ __launch_bounds__(256) void zero_kernel(float* __restrict__ y,
                                                   float* __restrict__ psum,
                                                   int* __restrict__ fcnt) {
  size_t idx = (size_t)blockIdx.x * 256 + threadIdx.x;
  float4 z = make_float4(0.f, 0.f, 0.f, 0.f);
  float4* p = (float4*)y;
#pragma unroll
  for (int j = 0; j < 4; ++j) p[idx + (size_t)j * 524288] = z;
  if (idx == 0) {
    y[YN] = 0.f;
    for (int e = 0; e < 8; ++e) { psum[e] = 0.f; fcnt[e] = 0; }
  }
}

// ---------------- fp32 -> bf16 (x) ----------------
__global__ __launch_bounds__(256) void convx_kernel(const float* __restrict__ in,
                                                    __bf16* __restrict__ out) {
  size_t i = ((size_t)blockIdx.x * 256 + threadIdx.x) * 8;
  float4 a = *(const float4*)(in + i);
  float4 b = *(const float4*)(in + i + 4);
  bf16x8 o;
  o[0] = (__bf16)a.x; o[1] = (__bf16)a.y; o[2] = (__bf16)a.z; o[3] = (__bf16)a.w;
  o[4] = (__bf16)b.x; o[5] = (__bf16)b.y; o[6] = (__bf16)b.z; o[7] = (__bf16)b.w;
  *(bf16x8*)(out + i) = o;
}

// ---------------- transpose + convert weights: in[R][C] f32 -> out[C][R] bf16 ----------------
__global__ __launch_bounds__(256) void tconv_kernel(const float* __restrict__ in,
                                                    __bf16* __restrict__ out, int R, int C) {
  __shared__ float t[32][33];
  size_t mo = (size_t)blockIdx.z * R * C;
  const float* ip = in + mo;
  __bf16* op = out + mo;
  int c0 = blockIdx.x * 32, r0 = blockIdx.y * 32;
  int tx = threadIdx.x, ty = threadIdx.y;  // block (32,8)
#pragma unroll
  for (int k2 = 0; k2 < 4; ++k2)
    t[ty + k2 * 8][tx] = ip[(size_t)(r0 + ty + k2 * 8) * C + c0 + tx];
  __syncthreads();
#pragma unroll
  for (int k2 = 0; k2 < 4; ++k2)
    op[(size_t)(c0 + ty + k2 * 8) * R + r0 + tx] = (__bf16)t[tx][ty + k2 * 8];
}

// ---------------- router: fp32 logits, softmax, top-2, renorm, aux stats ----------------
__global__ __launch_bounds__(256) void router_kernel(
    const float* __restrict__ x, const float* __restrict__ rw,
    int2* __restrict__ e01, float2* __restrict__ p01,
    int* __restrict__ tok_row, float* __restrict__ scale_row,
    float* __restrict__ psum, int* __restrict__ fcnt) {
  __shared__ float rwl[8 * 1024];
  __shared__ float ps[8];
  __shared__ int fc[8];
  int tid = threadIdx.x;
  if (tid < 8) { ps[tid] = 0.f; fc[tid] = 0; }
  float4* rl4 = (float4*)rwl;
  const float4* rg4 = (const float4*)rw;
#pragma unroll
  for (int j = 0; j < 8; ++j) rl4[tid + 256 * j] = rg4[tid + 256 * j];
  __syncthreads();
  int lane = tid & 63, wid = tid >> 6;
  for (int it = 0; it < 8; ++it) {
    int t = blockIdx.x * 32 + wid * 8 + it;
    const float4* xt = (const float4*)(x + (size_t)t * DDIM);
    float a[8];
#pragma unroll
    for (int e = 0; e < 8; ++e) a[e] = 0.f;
#pragma unroll
    for (int jj = 0; jj < 4; ++jj) {
      float4 v = xt[lane * 4 + jj];
#pragma unroll
      for (int e = 0; e < 8; ++e) {
        float4 w = rl4[e * 256 + lane * 4 + jj];
        a[e] += v.x * w.x + v.y * w.y + v.z * w.z + v.w * w.w;
      }
    }
#pragma unroll
    for (int off = 32; off >= 1; off >>= 1)
#pragma unroll
      for (int e = 0; e < 8; ++e) a[e] += __shfl_xor(a[e], off);
    if (lane == 0) {
      int am = 0; float m = a[0];
      for (int e = 1; e < 8; ++e) if (a[e] > m) { m = a[e]; am = e; }
      float s = 0.f, ex[8];
      for (int e = 0; e < 8; ++e) { ex[e] = expf(a[e] - m); s += ex[e]; }
      float inv = 1.f / s;
      int am2 = -1; float m2 = -3.4e38f;
      for (int e = 0; e < 8; ++e) if (e != am && a[e] > m2) { m2 = a[e]; am2 = e; }
      float p0 = ex[am] * inv, p1 = ex[am2] * inv;
      float rn = 1.f / (p0 + p1 + 1e-9f);
      e01[t] = make_int2(am, am2);
      p01[t] = make_float2(p0 * rn, p1 * rn);
      tok_row[t] = t;            // shared-group rows: identity gather, weight 1
      scale_row[t] = 1.f;
      atomicAdd(&fc[am], 1);
      for (int e = 0; e < 8; ++e) atomicAdd(&ps[e], ex[e] * inv);
    }
  }
  __syncthreads();
  if (tid < 8) { atomicAdd(&psum[tid], ps[tid]); atomicAdd(&fcnt[tid], fc[tid]); }
}

// ---------------- dispatch: stable rank within expert (token-major order), capacity drop ----------------
__global__ __launch_bounds__(256) void dispatch_kernel(
    const int2* __restrict__ e01, const float2* __restrict__ p01,
    int* __restrict__ tok_row, float* __restrict__ scale_row, int* __restrict__ counts) {
  __shared__ int lcnt[256][8];
  int tid = threadIdx.x;
  int my[8];
#pragma unroll
  for (int e = 0; e < 8; ++e) my[e] = 0;
  int base = tid * 64;  // 256 threads * 64 entries = 16384 = N*K, contiguous => stable
  for (int j = 0; j < 64; ++j) {
    int ent = base + j; int t = ent >> 1;
    int2 ee = e01[t];
    int ex = (ent & 1) ? ee.y : ee.x;
    my[ex]++;
  }
#pragma unroll
  for (int e = 0; e < 8; ++e) lcnt[tid][e] = my[e];
  __syncthreads();
  if (tid < 8) {
    int run = 0;
    for (int i = 0; i < 256; ++i) { int c = lcnt[i][tid]; lcnt[i][tid] = run; run += c; }
    counts[tid] = run < CAP ? run : CAP;
  }
  __syncthreads();
  int offs[8];
#pragma unroll
  for (int e = 0; e < 8; ++e) offs[e] = lcnt[tid][e];
  for (int j = 0; j < 64; ++j) {
    int ent = base + j; int t = ent >> 1; int k = ent & 1;
    int2 ee = e01[t];
    int ex = k ? ee.y : ee.x;
    float pr = k ? p01[t].y : p01[t].x;
    int pos = offs[ex]++;
    if (pos < CAP) {
      int row = NTOK + ex * CAP + pos;
      tok_row[row] = t;
      scale_row[row] = pr;
    }
  }
}

// ---------------- grouped GEMM, BMxBN tile, BK=32, 8 waves, depth-3 pipeline ----------------
// 4 LDS buffers; stage(t+3) issued at step t; one raw s_barrier per step.
// vmcnt ledger (3 loads/wave/stage): steady state vmcnt(6) => stages <= t+1
// complete; drain tail 6 -> 3 -> 0 once issuing stops (R4 bug: kept 6).
// Cross-wave visibility: each wave waits its own vmcnt BEFORE the barrier;
// after the barrier all waves' stage(t+1) loads have landed.
// XOR swizzle (BK=32): LDS[row][c'] holds global chunk c'^((row>>1)&3).
// EPI==1: H = bf16(relu(acc)^2)   EPI==2: atomicAdd(y[tok][col], acc*scale)
template <int BM, int BN, int KD, int NDT, int WNV, bool GATHER, int EPI>
__global__ __launch_bounds__(512, 2) void gemm_kernel(
    const __bf16* __restrict__ A, const __bf16* __restrict__ B,
    __bf16* __restrict__ Hout, float* __restrict__ Yout,
    const int* __restrict__ counts, const int* __restrict__ tok_row,
    const float* __restrict__ scale_row) {
  constexpr int NCT = NDT / BN;
  constexpr int T = KD / 32;          // K-steps (32 or 44)
  constexpr int AI = BM / 16;         // A stage instrs per step (16-row blocks)
  constexpr int BI = BN / 16;         // B stage instrs per step
  constexpr int LI = (AI + BI) / 8;   // per-wave stage instrs (=3)
  constexpr int SH = NTOK / BM;
  constexpr int ET = CAP / BM;
  // XCD bijective remap + 4-rt chunks (nwg%8==0, nwg%(4*NCT)==0 hold)
  int nwg = gridDim.x;
  int lin = (blockIdx.x & 7) * (nwg >> 3) + (blockIdx.x >> 3);
  int rem = lin % (4 * NCT);
  int rt = (lin / (4 * NCT)) * 4 + (rem & 3);
  int ct = rem >> 2;

  int g, i0, rowbase;
  if (rt < SH) { g = 8; rowbase = 0; i0 = rt * BM; }
  else { int r = rt - SH; g = r / ET; i0 = (r % ET) * BM; rowbase = NTOK + g * CAP; }
  int cnt = (g == 8) ? NTOK : counts[g];
  if (i0 >= cnt) return;  // uniform early-exit

  __shared__ __align__(16) __bf16 As[4][BM * 32];
  __shared__ __align__(16) __bf16 Bs[4][BN * 32];
  __shared__ int   toksL[BM];
  __shared__ float sclL[BM];

  int tid = threadIdx.x, lane = tid & 63, wid = tid >> 6;

  if (tid < BM) {
    int i = i0 + tid; if (i > cnt - 1) i = cnt - 1;  // pad rows duplicate last valid
    toksL[tid] = tok_row[rowbase + i];
    if (EPI == 2) sclL[tid] = scale_row[rowbase + i];
  }
  __syncthreads();

  // per-lane stage setup: instr j covers 16 rows x 64B; lane -> row j*16+(lane>>2),
  // chunk (lane&3), source chunk XOR-swizzled by (row>>1)&3.
  const char* gsrc[LI];
  int ldsoff[LI];
  bool isA[LI];
  const char* Bg = (const char*)B + (size_t)g * NDT * KD * 2;
#pragma unroll
  for (int q = 0; q < LI; ++q) {
    int j = wid * LI + q;
    int rsub = lane >> 2;
    int chunk = lane & 3;
    if (j < AI) {
      int row = j * 16 + rsub;
      size_t arow = GATHER ? (size_t)toksL[row] : (size_t)(rowbase + i0 + row);
      int csw = chunk ^ ((row >> 1) & 3);
      gsrc[q] = (const char*)A + arow * (size_t)(KD * 2) + csw * 16;
      ldsoff[q] = j * 1024;
      isA[q] = true;
    } else {
      int jb = j - AI;
      int row = jb * 16 + rsub;
      int ib = ct * BN + row;
      int csw = chunk ^ ((row >> 1) & 3);
      gsrc[q] = Bg + (size_t)ib * (KD * 2) + csw * 16;
      ldsoff[q] = jb * 1024;
      isA[q] = false;
    }
  }

  f32x4 acc[4][4];
#pragma unroll
  for (int m2 = 0; m2 < 4; ++m2)
#pragma unroll
    for (int n2 = 0; n2 < 4; ++n2) acc[m2][n2] = f32x4{0.f, 0.f, 0.f, 0.f};

  int wr = wid / WNV, wc = wid % WNV;  // wave tile 64x64 at (wr*64, wc*64)
  // hoisted LDS read byte-offsets within a buffer
  int rdA[4], rdB[4];
#pragma unroll
  for (int m2 = 0; m2 < 4; ++m2) {
    int row = wr * 64 + m2 * 16 + (lane & 15);
    int cs = (lane >> 4) ^ ((row >> 1) & 3);
    rdA[m2] = row * 64 + cs * 16;
  }
#pragma unroll
  for (int n2 = 0; n2 < 4; ++n2) {
    int row = wc * 64 + n2 * 16 + (lane & 15);
    int cs = (lane >> 4) ^ ((row >> 1) & 3);
    rdB[n2] = row * 64 + cs * 16;
  }

  auto stage = [&](int buf, int t) {
#pragma unroll
    for (int q = 0; q < LI; ++q) {
      char* l = (char*)(isA[q] ? &As[buf][0] : &Bs[buf][0]) + ldsoff[q];
      load_lds16(gsrc[q] + (size_t)t * 64, l);
    }
  };
  auto compute = [&](int buf) {
    bf16x8 af[4], bfr[4];
#pragma unroll
    for (int m2 = 0; m2 < 4; ++m2)
      af[m2] = *(const bf16x8*)((const char*)&As[buf][0] + rdA[m2]);
#pragma unroll
    for (int n2 = 0; n2 < 4; ++n2)
      bfr[n2] = *(const bf16x8*)((const char*)&Bs[buf][0] + rdB[n2]);
    __builtin_amdgcn_s_setprio(1);
#pragma unroll
    for (int m2 = 0; m2 < 4; ++m2)
#pragma unroll
      for (int n2 = 0; n2 < 4; ++n2)
        acc[m2][n2] = __builtin_amdgcn_mfma_f32_16x16x32_bf16(af[m2], bfr[n2], acc[m2][n2], 0, 0, 0);
    __builtin_amdgcn_s_setprio(0);
  };
  auto syncstep = [&](int n) {   // wait own loads (all but newest n), then collective barrier
    if (n == 0)      asm volatile("s_waitcnt vmcnt(0)" ::: "memory");
    else if (n == 3) asm volatile("s_waitcnt vmcnt(3)" ::: "memory");
    else             asm volatile("s_waitcnt vmcnt(6)" ::: "memory");
    __builtin_amdgcn_s_barrier();
    __builtin_amdgcn_sched_barrier(0);  // raw s_barrier is not an LLVM fence: pin reads below
  };

  // prologue: fill pipeline 3 deep; vmcnt(6) => buf0's own loads complete
  stage(0, 0);
  stage(1, 1);
  stage(2, 2);
  syncstep(6);
  // steady state: stage(t+3) in flight; vmcnt(6) => stage(t+1) complete
#pragma unroll 4
  for (int t = 0; t < T - 3; ++t) {
    stage((t + 3) & 3, t + 3);
    compute(t & 3);
    syncstep(6);
  }
  // drain tail: no new stages; 6 -> 3 -> 0 outstanding
  compute((T - 3) & 3);
  syncstep(3);                 // stage(T-2) complete
  compute((T - 2) & 3);
  syncstep(0);                 // stage(T-1) complete
  compute((T - 1) & 3);

  // epilogue; C/D frag: col = lane&15, row = (lane>>4)*4 + reg  [verified m89/m91]
#pragma unroll
  for (int m2 = 0; m2 < 4; ++m2) {
    int rb = wr * 64 + m2 * 16 + ((lane >> 4) << 2);
#pragma unroll
    for (int n2 = 0; n2 < 4; ++n2) {
      int col = ct * BN + wc * 64 + n2 * 16 + (lane & 15);
#pragma unroll
      for (int r = 0; r < 4; ++r) {
        int grow = i0 + rb + r;
        if (grow < cnt) {
          float v = acc[m2][n2][r];
          if constexpr (EPI == 1) {
            v = fmaxf(v, 0.f);
            Hout[(size_t)(rowbase + grow) * NDT + col] = (__bf16)(v * v);
          } else {
            atomicAdd(&Yout[(size_t)toksL[rb + r] * NDT + col], v * sclL[rb + r]);
          }
        }
      }
    }
  }
}

// ---------------- aux loss ----------------
__global__ void aux_kernel(const float* __restrict__ psum, const int* __restrict__ fcnt,
                           float* __restrict__ out) {
  float s = 0.f;
  for (int e = 0; e < 8; ++e) s += ((float)fcnt[e] / 8192.f) * (psum[e] / 8192.f);
  *out = 0.08f * s;  // AUX_COEF * E = 0.01 * 8
}

extern "C" void kernel_launch(void* const* d_in, const int* in_sizes, int n_in,
                              void* d_out, int out_size, void* d_ws, size_t ws_size,
                              hipStream_t stream) {
  const float* x      = (const float*)d_in[0];
  const float* rw     = (const float*)d_in[1];
  const float* wfc    = (const float*)d_in[2];
  const float* wproj  = (const float*)d_in[3];
  const float* wsfc   = (const float*)d_in[4];
  const float* wsproj = (const float*)d_in[5];
  float* y = (float*)d_out;

  char* ws = (char*)d_ws;
  size_t off = 0;
  auto alloc = [&](size_t bytes) {
    void* p = ws + off;
    off += (bytes + 1023) & ~(size_t)1023;
    return p;
  };
  __bf16* xbf      = (__bf16*)alloc((size_t)NTOK * DDIM * 2);          // 16 MB
  __bf16* B1       = (__bf16*)alloc((size_t)9 * HDIM * DDIM * 2);      // 26 MB [9][1408][1024]
  __bf16* B2       = (__bf16*)alloc((size_t)9 * DDIM * HDIM * 2);      // 26 MB [9][1024][1408]
  __bf16* H        = (__bf16*)alloc((size_t)NROWS * HDIM * 2);         // 81 MB
  int*    tok_row  = (int*)alloc((size_t)NROWS * 4);
  float*  scale_row= (float*)alloc((size_t)NROWS * 4);
  int2*   e01      = (int2*)alloc((size_t)NTOK * 8);
  float2* p01      = (float2*)alloc((size_t)NTOK * 8);
  int*    counts   = (int*)alloc(1024);
  float*  psum     = (float*)alloc(1024);
  int*    fcnt     = (int*)alloc(1024);
  (void)ws_size; (void)out_size; (void)in_sizes; (void)n_in;

  zero_kernel<<<2048, 256, 0, stream>>>(y, psum, fcnt);
  convx_kernel<<<4096, 256, 0, stream>>>(x, xbf);
  dim3 tb(32, 8);
  tconv_kernel<<<dim3(44, 32, 8), tb, 0, stream>>>(wfc, B1, 1024, 1408);
  tconv_kernel<<<dim3(44, 32, 1), tb, 0, stream>>>(wsfc, B1 + (size_t)8 * HDIM * DDIM, 1024, 1408);
  tconv_kernel<<<dim3(32, 44, 8), tb, 0, stream>>>(wproj, B2, 1408, 1024);
  tconv_kernel<<<dim3(32, 44, 1), tb, 0, stream>>>(wsproj, B2 + (size_t)8 * DDIM * HDIM, 1408, 1024);
  router_kernel<<<256, 256, 0, stream>>>(x, rw, e01, p01, tok_row, scale_row, psum, fcnt);
  dispatch_kernel<<<1, 256, 0, stream>>>(e01, p01, tok_row, scale_row, counts);
  // GEMM1: H = relu(gather(x) @ B1)^2 ; 256x128 tiles: (32 + 8*10) rt * 11 ct = 1232
  gemm_kernel<256, 128, 1024, 1408, 2, true, 1><<<1232, 512, 0, stream>>>(
      xbf, B1, H, nullptr, counts, tok_row, scale_row);
  // GEMM2: y[tok] += scale * (H @ B2) ; 128x256 tiles: (64 + 8*20) rt * 4 ct = 896
  gemm_kernel<128, 256, 1408, 1024, 4, false, 2><<<896, 512, 0, stream>>>(
      H, B2, nullptr, y, counts, tok_row, scale_row);
  aux_kernel<<<1, 1, 0, stream>>>(psum, fcnt, y + YN);
}